// Round 7
// baseline (1074.897 us; speedup 1.0000x reference)
//
#include <hip/hip_runtime.h>

#define BATCH 2048
#define F0N 39
#define EMBN 16
#define LN 128
#define HN 64
#define DXN 13
#define DINN 829
#define EPSF 1e-3f

// ---------------------------------------------------------------------------
// K1: fused gather + einsum1 + relu/slice + einsum2 + multi_cross.
// 2 batches per 256-thread block (halves share the W0/W1 stream via L1/L2).
// Per 128-thread half: thread = (lt in [0,32), dg in [0,4)) owns l=lt*4..+3,
// d=dg*4..+3. Factored form: s[l][d] = sum_j W[ij,l]*xj[d]; acc += xi[d]*s.
// 1 FMA per (i,j,l,d) instead of 2.
// ---------------------------------------------------------------------------
__global__ __launch_bounds__(256) void cross_kernel(
    const float* __restrict__ input_x,
    const int*   __restrict__ input_hash,
    const float* __restrict__ table,
    const float* __restrict__ W0,
    const float* __restrict__ W1,
    float* __restrict__ raw)            // B x 829 (d_out inputs region, raw)
{
    __shared__ float x0s[2][F0N][EMBN];
    __shared__ float nh[2][HN][EMBN];
    __shared__ float red[2][LN][4];

    const int half = threadIdx.x >> 7;
    const int t2   = threadIdx.x & 127;
    const int b    = blockIdx.x * 2 + half;
    const int lt   = t2 & 31;
    const int dg   = t2 >> 5;

    // ---- gather embeddings; write hash_flat + input_x into raw inputs ----
    for (int idx = t2; idx < F0N * EMBN; idx += 128) {
        const int f = idx >> 4, d = idx & 15;
        const int row = input_hash[b * F0N + f];
        const float v = table[(size_t)row * EMBN + d];
        x0s[half][f][d] = v;
        raw[(size_t)b * DINN + DXN + idx] = v;
    }
    if (t2 < DXN) raw[(size_t)b * DINN + t2] = input_x[b * DXN + t2];
    __syncthreads();

    // ---- einsum1: c0[l,d] = sum_i x[i,d] * (sum_j W0[ij,l] x[j,d]) ----
    float acc[4][4];
#pragma unroll
    for (int a = 0; a < 4; ++a)
#pragma unroll
        for (int c = 0; c < 4; ++c) acc[a][c] = 0.f;

    {
        const float* wbase = W0 + lt * 4;
        for (int i = 0; i < F0N; ++i) {
            float s[4][4];
#pragma unroll
            for (int a = 0; a < 4; ++a)
#pragma unroll
                for (int c = 0; c < 4; ++c) s[a][c] = 0.f;
            const float* wrow = wbase + (size_t)(i * F0N) * LN;
#pragma unroll 3
            for (int j = 0; j < F0N; ++j) {
                float wv[4], xj[4];
                *(float4*)wv = *(const float4*)(wrow + (size_t)j * LN);
                *(float4*)xj = *(const float4*)&x0s[half][j][dg * 4];
#pragma unroll
                for (int a = 0; a < 4; ++a)
#pragma unroll
                    for (int c = 0; c < 4; ++c)
                        s[a][c] = fmaf(wv[a], xj[c], s[a][c]);
            }
            float xi[4];
            *(float4*)xi = *(const float4*)&x0s[half][i][dg * 4];
#pragma unroll
            for (int a = 0; a < 4; ++a)
#pragma unroll
                for (int c = 0; c < 4; ++c)
                    acc[a][c] = fmaf(xi[c], s[a][c], acc[a][c]);
        }
    }

    // ---- relu; l<64 -> next_h (LDS); l>=64 -> direct0 partial d-sums ----
#pragma unroll
    for (int a = 0; a < 4; ++a) {
        const int l = lt * 4 + a;
        const float v0 = fmaxf(acc[a][0], 0.f);
        const float v1 = fmaxf(acc[a][1], 0.f);
        const float v2 = fmaxf(acc[a][2], 0.f);
        const float v3 = fmaxf(acc[a][3], 0.f);
        if (l < HN) {
            float4 v; v.x = v0; v.y = v1; v.z = v2; v.w = v3;
            *(float4*)&nh[half][l][dg * 4] = v;
        } else {
            red[half][l][dg] = v0 + v1 + v2 + v3;
        }
    }
    __syncthreads();

    // multi_cross[0..63] = sum_d direct0
    if (t2 < HN) {
        const int l = HN + t2;
        const float sum = red[half][l][0] + red[half][l][1] +
                          red[half][l][2] + red[half][l][3];
        raw[(size_t)b * DINN + DXN + F0N * EMBN + t2] = sum;
    }

    // ---- einsum2: direct1[l,d] = sum_i x[i,d] * (sum_j W1[ij,l] nh[j,d]) ----
    float acc2[4][4];
#pragma unroll
    for (int a = 0; a < 4; ++a)
#pragma unroll
        for (int c = 0; c < 4; ++c) acc2[a][c] = 0.f;

    {
        const float* wbase = W1 + lt * 4;
        for (int i = 0; i < F0N; ++i) {
            float s[4][4];
#pragma unroll
            for (int a = 0; a < 4; ++a)
#pragma unroll
                for (int c = 0; c < 4; ++c) s[a][c] = 0.f;
            const float* wrow = wbase + (size_t)(i * HN) * LN;
#pragma unroll 4
            for (int j = 0; j < HN; ++j) {
                float wv[4], xj[4];
                *(float4*)wv = *(const float4*)(wrow + (size_t)j * LN);
                *(float4*)xj = *(const float4*)&nh[half][j][dg * 4];
#pragma unroll
                for (int a = 0; a < 4; ++a)
#pragma unroll
                    for (int c = 0; c < 4; ++c)
                        s[a][c] = fmaf(wv[a], xj[c], s[a][c]);
            }
            float xi[4];
            *(float4*)xi = *(const float4*)&x0s[half][i][dg * 4];
#pragma unroll
            for (int a = 0; a < 4; ++a)
#pragma unroll
                for (int c = 0; c < 4; ++c)
                    acc2[a][c] = fmaf(xi[c], s[a][c], acc2[a][c]);
        }
    }
    __syncthreads();   // direct0 reads of `red` complete; safe to reuse

#pragma unroll
    for (int a = 0; a < 4; ++a) {
        const int l = lt * 4 + a;
        red[half][l][dg] = fmaxf(acc2[a][0], 0.f) + fmaxf(acc2[a][1], 0.f) +
                           fmaxf(acc2[a][2], 0.f) + fmaxf(acc2[a][3], 0.f);
    }
    __syncthreads();

    // multi_cross[64..191] = sum_d direct1
    {
        const int l = t2;   // 0..127
        const float sum = red[half][l][0] + red[half][l][1] +
                          red[half][l][2] + red[half][l][3];
        raw[(size_t)b * DINN + DXN + F0N * EMBN + HN + l] = sum;
    }
}

// ---------------------------------------------------------------------------
// BN1 stats, two-stage deterministic (no atomics).
// ---------------------------------------------------------------------------
__global__ __launch_bounds__(256) void stats1a_kernel(
    const float* __restrict__ raw, float* __restrict__ partials)
{
    const int g = blockIdx.x;          // 32 row-chunks of 64 rows
    const int r0 = g * 64;
    for (int c = threadIdx.x; c < DINN; c += 256) {
        float s = 0.f, q = 0.f;
#pragma unroll 8
        for (int r = r0; r < r0 + 64; ++r) {
            const float v = raw[(size_t)r * DINN + c];
            s += v; q = fmaf(v, v, q);
        }
        partials[(size_t)(g * 832 + c) * 2 + 0] = s;
        partials[(size_t)(g * 832 + c) * 2 + 1] = q;
    }
}

__global__ __launch_bounds__(256) void stats1b_kernel(
    const float* __restrict__ partials,
    const float* __restrict__ gamma, const float* __restrict__ beta,
    float* __restrict__ scale, float* __restrict__ shift)
{
    const int c = blockIdx.x * 256 + threadIdx.x;
    if (c >= DINN) return;
    float s = 0.f, q = 0.f;
#pragma unroll 8
    for (int g = 0; g < 32; ++g) {
        s += partials[(size_t)(g * 832 + c) * 2 + 0];
        q += partials[(size_t)(g * 832 + c) * 2 + 1];
    }
    const float mean = s * (1.f / BATCH);
    const float var  = q * (1.f / BATCH) - mean * mean;
    const float sc   = gamma[c] * rsqrtf(var + EPSF);
    scale[c] = sc;
    shift[c] = beta[c] - mean * sc;
}

// ---------------------------------------------------------------------------
// Normalize inputs in place (d_out region) + inputs @ w3 + b3 -> t3.
// 4 rows per 256-thread block; each wave owns one row (64 output cols).
// ---------------------------------------------------------------------------
__global__ __launch_bounds__(256) void mlp1_kernel(
    float* __restrict__ io,            // B x 829, raw in / normalized out
    const float* __restrict__ scale, const float* __restrict__ shift,
    const float* __restrict__ w3, const float* __restrict__ b3,
    float* __restrict__ t3)
{
    __shared__ float xin[4][832];
    const int sub = threadIdx.x >> 6;
    const int n   = threadIdx.x & 63;
    const int r   = blockIdx.x * 4 + sub;
    float* rowp = io + (size_t)r * DINN;
    for (int c = n; c < DINN; c += 64) {
        const float v = fmaf(rowp[c], scale[c], shift[c]);
        xin[sub][c] = v;
        rowp[c] = v;
    }
    __syncthreads();
    float acc = b3[n];
#pragma unroll 8
    for (int k = 0; k < DINN; ++k)
        acc = fmaf(xin[sub][k], w3[k * 64 + n], acc);
    t3[r * 64 + n] = acc;
}

// ---------------------------------------------------------------------------
// BN stats over t3 (64 cols) -> scale4/shift4. Single 1024-thread block.
// ---------------------------------------------------------------------------
__global__ __launch_bounds__(1024) void stats3_kernel(
    const float* __restrict__ t3,
    const float* __restrict__ gamma, const float* __restrict__ beta,
    float* __restrict__ sc, float* __restrict__ sh)
{
    __shared__ float redS[16][64];
    __shared__ float redQ[16][64];
    const int c = threadIdx.x & 63;
    const int chunk = threadIdx.x >> 6;    // 16 chunks x 128 rows
    float s = 0.f, q = 0.f;
#pragma unroll 4
    for (int r = chunk * 128; r < chunk * 128 + 128; ++r) {
        const float v = t3[r * 64 + c];
        s += v; q = fmaf(v, v, q);
    }
    redS[chunk][c] = s; redQ[chunk][c] = q;
    __syncthreads();
    if (threadIdx.x < 64) {
        float S = 0.f, Q = 0.f;
#pragma unroll
        for (int k = 0; k < 16; ++k) { S += redS[k][c]; Q += redQ[k][c]; }
        const float mean = S * (1.f / BATCH);
        const float var  = Q * (1.f / BATCH) - mean * mean;
        const float scv  = gamma[c] * rsqrtf(var + EPSF);
        sc[c] = scv;
        sh[c] = beta[c] - mean * scv;
    }
}

// ---------------------------------------------------------------------------
// h3 = relu(bn4(t3)); t4 = h3 @ w4 + b4. 4 rows per 128-thread block.
// ---------------------------------------------------------------------------
__global__ __launch_bounds__(128) void mlp2_kernel(
    const float* __restrict__ t3,
    const float* __restrict__ sc4, const float* __restrict__ sh4,
    const float* __restrict__ w4, const float* __restrict__ b4,
    float* __restrict__ t4)
{
    __shared__ float h3[4][64];
    const int sub = threadIdx.x >> 5;
    const int n   = threadIdx.x & 31;
    const int r   = blockIdx.x * 4 + sub;
#pragma unroll
    for (int k = n; k < 64; k += 32) {
        const float v = fmaf(t3[r * 64 + k], sc4[k], sh4[k]);
        h3[sub][k] = fmaxf(v, 0.f);
    }
    __syncthreads();
    float acc = b4[n];
#pragma unroll
    for (int k = 0; k < 64; ++k)
        acc = fmaf(h3[sub][k], w4[k * 32 + n], acc);
    t4[r * 32 + n] = acc;
}

// ---------------------------------------------------------------------------
// BN stats over t4 (32 cols) -> scale5/shift5. Single 1024-thread block.
// ---------------------------------------------------------------------------
__global__ __launch_bounds__(1024) void stats4_kernel(
    const float* __restrict__ t4,
    const float* __restrict__ gamma, const float* __restrict__ beta,
    float* __restrict__ sc, float* __restrict__ sh)
{
    __shared__ float redS[32][32];
    __shared__ float redQ[32][32];
    const int c = threadIdx.x & 31;
    const int chunk = threadIdx.x >> 5;    // 32 chunks x 64 rows
    float s = 0.f, q = 0.f;
#pragma unroll 4
    for (int r = chunk * 64; r < chunk * 64 + 64; ++r) {
        const float v = t4[r * 32 + c];
        s += v; q = fmaf(v, v, q);
    }
    redS[chunk][c] = s; redQ[chunk][c] = q;
    __syncthreads();
    if (threadIdx.x < 32) {
        float S = 0.f, Q = 0.f;
#pragma unroll
        for (int k = 0; k < 32; ++k) { S += redS[k][c]; Q += redQ[k][c]; }
        const float mean = S * (1.f / BATCH);
        const float var  = Q * (1.f / BATCH) - mean * mean;
        const float scv  = gamma[c] * rsqrtf(var + EPSF);
        sc[c] = scv;
        sh[c] = beta[c] - mean * scv;
    }
}

// ---------------------------------------------------------------------------
// h4 = relu(bn5(t4)); out = h4 @ w5 + b5. 8 rows per 256-thread block.
// ---------------------------------------------------------------------------
__global__ __launch_bounds__(256) void final_kernel(
    const float* __restrict__ t4,
    const float* __restrict__ sc5, const float* __restrict__ sh5,
    const float* __restrict__ w5, const float* __restrict__ b5,
    float* __restrict__ out)
{
    const int sub = threadIdx.x >> 5;
    const int n   = threadIdx.x & 31;
    const int r   = blockIdx.x * 8 + sub;
    float v = fmaf(t4[r * 32 + n], sc5[n], sh5[n]);
    v = fmaxf(v, 0.f) * w5[n];
#pragma unroll
    for (int off = 16; off > 0; off >>= 1)
        v += __shfl_xor(v, off);
    if (n == 0) out[r] = v + b5[0];
}

// ---------------------------------------------------------------------------
extern "C" void kernel_launch(void* const* d_in, const int* in_sizes, int n_in,
                              void* d_out, int out_size, void* d_ws, size_t ws_size,
                              hipStream_t stream) {
    const float* input_x    = (const float*)d_in[0];
    const int*   input_hash = (const int*)  d_in[1];
    const float* table      = (const float*)d_in[2];
    const float* W0         = (const float*)d_in[3];
    const float* W1         = (const float*)d_in[4];
    const float* gamma1     = (const float*)d_in[5];
    const float* beta1      = (const float*)d_in[6];
    const float* w3         = (const float*)d_in[7];
    const float* b3         = (const float*)d_in[8];
    const float* gamma4     = (const float*)d_in[9];
    const float* beta4      = (const float*)d_in[10];
    const float* w4         = (const float*)d_in[11];
    const float* b4         = (const float*)d_in[12];
    const float* gamma5     = (const float*)d_in[13];
    const float* beta5      = (const float*)d_in[14];
    const float* w5         = (const float*)d_in[15];
    const float* b5         = (const float*)d_in[16];

    float* out        = (float*)d_out;         // B
    float* io_inputs  = out + BATCH;           // B x 829 (raw, then normalized)

    float* ws       = (float*)d_ws;
    float* partials = ws;                      // 32*832*2
    float* scale1   = partials + 32 * 832 * 2; // 832
    float* shift1   = scale1 + 832;            // 832
    float* t3       = shift1 + 832;            // B*64
    float* sc4      = t3 + BATCH * 64;         // 64
    float* sh4      = sc4 + 64;                // 64
    float* t4       = sh4 + 64;                // B*32
    float* sc5      = t4 + BATCH * 32;         // 32
    float* sh5      = sc5 + 32;                // 32

    cross_kernel  <<<BATCH / 2, 256, 0, stream>>>(input_x, input_hash, table, W0, W1, io_inputs);
    stats1a_kernel<<<32,        256, 0, stream>>>(io_inputs, partials);
    stats1b_kernel<<<4,         256, 0, stream>>>(partials, gamma1, beta1, scale1, shift1);
    mlp1_kernel   <<<BATCH / 4, 256, 0, stream>>>(io_inputs, scale1, shift1, w3, b3, t3);
    stats3_kernel <<<1,        1024, 0, stream>>>(t3, gamma4, beta4, sc4, sh4);
    mlp2_kernel   <<<BATCH / 4, 128, 0, stream>>>(t3, sc4, sh4, w4, b4, t4);
    stats4_kernel <<<1,        1024, 0, stream>>>(t4, gamma5, beta5, sc5, sh5);
    final_kernel  <<<BATCH / 8, 256, 0, stream>>>(t4, sc5, sh5, w5, b5, out);
}

// Round 11
// 1030.899 us; speedup vs baseline: 1.0427x; 1.0427x over previous
//
#include <hip/hip_runtime.h>

#define BATCH 2048
#define F0N 39
#define EMBN 16
#define LN 128
#define HN 64
#define DXN 13
#define DINN 829
#define EPSF 1e-3f

// ---------------------------------------------------------------------------
// K1: fused gather + einsum1 + relu/slice + einsum2 + multi_cross.
// 2 batches per 256-thread block. Thread (lt,dg) owns l=lt*4..+3, d=dg*4..+3.
// Factored: s[l][d] = sum_j W[ij,l]*xj[d]; acc += xi[d]*s.
// R7 fix: deep j-unroll (13 / 16) so the compiler keeps >=12 W-loads in
// flight per wave (was unroll 3 -> VALUBusy 49%, latency-bound; VGPR was 40
// with headroom to ~128 at 4 waves/SIMD).
// ---------------------------------------------------------------------------
__global__ __launch_bounds__(256) void cross_kernel(
    const float* __restrict__ input_x,
    const int*   __restrict__ input_hash,
    const float* __restrict__ table,
    const float* __restrict__ W0,
    const float* __restrict__ W1,
    float* __restrict__ raw)            // B x 829 (d_out inputs region, raw)
{
    __shared__ float x0s[2][F0N][EMBN];
    __shared__ float nh[2][HN][EMBN];
    __shared__ float red[2][LN][4];

    const int half = threadIdx.x >> 7;
    const int t2   = threadIdx.x & 127;
    const int b    = blockIdx.x * 2 + half;
    const int lt   = t2 & 31;
    const int dg   = t2 >> 5;

    // ---- gather embeddings; write hash_flat + input_x into raw inputs ----
    for (int idx = t2; idx < F0N * EMBN; idx += 128) {
        const int f = idx >> 4, d = idx & 15;
        const int row = input_hash[b * F0N + f];
        const float v = table[(size_t)row * EMBN + d];
        x0s[half][f][d] = v;
        raw[(size_t)b * DINN + DXN + idx] = v;
    }
    if (t2 < DXN) raw[(size_t)b * DINN + t2] = input_x[b * DXN + t2];
    __syncthreads();

    // ---- einsum1: c0[l,d] = sum_i x[i,d] * (sum_j W0[ij,l] x[j,d]) ----
    float acc[4][4];
#pragma unroll
    for (int a = 0; a < 4; ++a)
#pragma unroll
        for (int c = 0; c < 4; ++c) acc[a][c] = 0.f;

    {
        const float* wbase = W0 + lt * 4;
        for (int i = 0; i < F0N; ++i) {
            float xi[4];
            *(float4*)xi = *(const float4*)&x0s[half][i][dg * 4];

            float s[4][4];
#pragma unroll
            for (int a = 0; a < 4; ++a)
#pragma unroll
                for (int c = 0; c < 4; ++c) s[a][c] = 0.f;
            const float* wrow = wbase + (size_t)(i * F0N) * LN;
#pragma unroll 13
            for (int j = 0; j < F0N; ++j) {
                float wv[4], xj[4];
                *(float4*)wv = *(const float4*)(wrow + (size_t)j * LN);
                *(float4*)xj = *(const float4*)&x0s[half][j][dg * 4];
#pragma unroll
                for (int a = 0; a < 4; ++a)
#pragma unroll
                    for (int c = 0; c < 4; ++c)
                        s[a][c] = fmaf(wv[a], xj[c], s[a][c]);
            }
#pragma unroll
            for (int a = 0; a < 4; ++a)
#pragma unroll
                for (int c = 0; c < 4; ++c)
                    acc[a][c] = fmaf(xi[c], s[a][c], acc[a][c]);
        }
    }

    // ---- relu; l<64 -> next_h (LDS); l>=64 -> direct0 partial d-sums ----
#pragma unroll
    for (int a = 0; a < 4; ++a) {
        const int l = lt * 4 + a;
        const float v0 = fmaxf(acc[a][0], 0.f);
        const float v1 = fmaxf(acc[a][1], 0.f);
        const float v2 = fmaxf(acc[a][2], 0.f);
        const float v3 = fmaxf(acc[a][3], 0.f);
        if (l < HN) {
            float4 v; v.x = v0; v.y = v1; v.z = v2; v.w = v3;
            *(float4*)&nh[half][l][dg * 4] = v;
        } else {
            red[half][l][dg] = v0 + v1 + v2 + v3;
        }
    }
    __syncthreads();

    // multi_cross[0..63] = sum_d direct0
    if (t2 < HN) {
        const int l = HN + t2;
        const float sum = red[half][l][0] + red[half][l][1] +
                          red[half][l][2] + red[half][l][3];
        raw[(size_t)b * DINN + DXN + F0N * EMBN + t2] = sum;
    }

    // ---- einsum2: direct1[l,d] = sum_i x[i,d] * (sum_j W1[ij,l] nh[j,d]) ----
    float acc2[4][4];
#pragma unroll
    for (int a = 0; a < 4; ++a)
#pragma unroll
        for (int c = 0; c < 4; ++c) acc2[a][c] = 0.f;

    {
        const float* wbase = W1 + lt * 4;
        for (int i = 0; i < F0N; ++i) {
            float xi[4];
            *(float4*)xi = *(const float4*)&x0s[half][i][dg * 4];

            float s[4][4];
#pragma unroll
            for (int a = 0; a < 4; ++a)
#pragma unroll
                for (int c = 0; c < 4; ++c) s[a][c] = 0.f;
            const float* wrow = wbase + (size_t)(i * HN) * LN;
#pragma unroll 16
            for (int j = 0; j < HN; ++j) {
                float wv[4], xj[4];
                *(float4*)wv = *(const float4*)(wrow + (size_t)j * LN);
                *(float4*)xj = *(const float4*)&nh[half][j][dg * 4];
#pragma unroll
                for (int a = 0; a < 4; ++a)
#pragma unroll
                    for (int c = 0; c < 4; ++c)
                        s[a][c] = fmaf(wv[a], xj[c], s[a][c]);
            }
#pragma unroll
            for (int a = 0; a < 4; ++a)
#pragma unroll
                for (int c = 0; c < 4; ++c)
                    acc2[a][c] = fmaf(xi[c], s[a][c], acc2[a][c]);
        }
    }
    __syncthreads();   // direct0 reads of `red` complete; safe to reuse

#pragma unroll
    for (int a = 0; a < 4; ++a) {
        const int l = lt * 4 + a;
        red[half][l][dg] = fmaxf(acc2[a][0], 0.f) + fmaxf(acc2[a][1], 0.f) +
                           fmaxf(acc2[a][2], 0.f) + fmaxf(acc2[a][3], 0.f);
    }
    __syncthreads();

    // multi_cross[64..191] = sum_d direct1
    {
        const int l = t2;   // 0..127
        const float sum = red[half][l][0] + red[half][l][1] +
                          red[half][l][2] + red[half][l][3];
        raw[(size_t)b * DINN + DXN + F0N * EMBN + HN + l] = sum;
    }
}

// ---------------------------------------------------------------------------
// BN1 stats, two-stage deterministic (no atomics).
// ---------------------------------------------------------------------------
__global__ __launch_bounds__(256) void stats1a_kernel(
    const float* __restrict__ raw, float* __restrict__ partials)
{
    const int g = blockIdx.x;          // 32 row-chunks of 64 rows
    const int r0 = g * 64;
    for (int c = threadIdx.x; c < DINN; c += 256) {
        float s = 0.f, q = 0.f;
#pragma unroll 8
        for (int r = r0; r < r0 + 64; ++r) {
            const float v = raw[(size_t)r * DINN + c];
            s += v; q = fmaf(v, v, q);
        }
        partials[(size_t)(g * 832 + c) * 2 + 0] = s;
        partials[(size_t)(g * 832 + c) * 2 + 1] = q;
    }
}

__global__ __launch_bounds__(256) void stats1b_kernel(
    const float* __restrict__ partials,
    const float* __restrict__ gamma, const float* __restrict__ beta,
    float* __restrict__ scale, float* __restrict__ shift)
{
    const int c = blockIdx.x * 256 + threadIdx.x;
    if (c >= DINN) return;
    float s = 0.f, q = 0.f;
#pragma unroll 8
    for (int g = 0; g < 32; ++g) {
        s += partials[(size_t)(g * 832 + c) * 2 + 0];
        q += partials[(size_t)(g * 832 + c) * 2 + 1];
    }
    const float mean = s * (1.f / BATCH);
    const float var  = q * (1.f / BATCH) - mean * mean;
    const float sc   = gamma[c] * rsqrtf(var + EPSF);
    scale[c] = sc;
    shift[c] = beta[c] - mean * sc;
}

// ---------------------------------------------------------------------------
// Normalize inputs in place (d_out region) + inputs @ w3 + b3 -> t3.
// ---------------------------------------------------------------------------
__global__ __launch_bounds__(256) void mlp1_kernel(
    float* __restrict__ io,            // B x 829, raw in / normalized out
    const float* __restrict__ scale, const float* __restrict__ shift,
    const float* __restrict__ w3, const float* __restrict__ b3,
    float* __restrict__ t3)
{
    __shared__ float xin[4][832];
    const int sub = threadIdx.x >> 6;
    const int n   = threadIdx.x & 63;
    const int r   = blockIdx.x * 4 + sub;
    float* rowp = io + (size_t)r * DINN;
    for (int c = n; c < DINN; c += 64) {
        const float v = fmaf(rowp[c], scale[c], shift[c]);
        xin[sub][c] = v;
        rowp[c] = v;
    }
    __syncthreads();
    float acc = b3[n];
#pragma unroll 8
    for (int k = 0; k < DINN; ++k)
        acc = fmaf(xin[sub][k], w3[k * 64 + n], acc);
    t3[r * 64 + n] = acc;
}

// ---------------------------------------------------------------------------
// BN stats over t3 (64 cols) -> scale4/shift4. Single 1024-thread block.
// ---------------------------------------------------------------------------
__global__ __launch_bounds__(1024) void stats3_kernel(
    const float* __restrict__ t3,
    const float* __restrict__ gamma, const float* __restrict__ beta,
    float* __restrict__ sc, float* __restrict__ sh)
{
    __shared__ float redS[16][64];
    __shared__ float redQ[16][64];
    const int c = threadIdx.x & 63;
    const int chunk = threadIdx.x >> 6;    // 16 chunks x 128 rows
    float s = 0.f, q = 0.f;
#pragma unroll 4
    for (int r = chunk * 128; r < chunk * 128 + 128; ++r) {
        const float v = t3[r * 64 + c];
        s += v; q = fmaf(v, v, q);
    }
    redS[chunk][c] = s; redQ[chunk][c] = q;
    __syncthreads();
    if (threadIdx.x < 64) {
        float S = 0.f, Q = 0.f;
#pragma unroll
        for (int k = 0; k < 16; ++k) { S += redS[k][c]; Q += redQ[k][c]; }
        const float mean = S * (1.f / BATCH);
        const float var  = Q * (1.f / BATCH) - mean * mean;
        const float scv  = gamma[c] * rsqrtf(var + EPSF);
        sc[c] = scv;
        sh[c] = beta[c] - mean * scv;
    }
}

// ---------------------------------------------------------------------------
// h3 = relu(bn4(t3)); t4 = h3 @ w4 + b4. 4 rows per 128-thread block.
// ---------------------------------------------------------------------------
__global__ __launch_bounds__(128) void mlp2_kernel(
    const float* __restrict__ t3,
    const float* __restrict__ sc4, const float* __restrict__ sh4,
    const float* __restrict__ w4, const float* __restrict__ b4,
    float* __restrict__ t4)
{
    __shared__ float h3[4][64];
    const int sub = threadIdx.x >> 5;
    const int n   = threadIdx.x & 31;
    const int r   = blockIdx.x * 4 + sub;
#pragma unroll
    for (int k = n; k < 64; k += 32) {
        const float v = fmaf(t3[r * 64 + k], sc4[k], sh4[k]);
        h3[sub][k] = fmaxf(v, 0.f);
    }
    __syncthreads();
    float acc = b4[n];
#pragma unroll
    for (int k = 0; k < 64; ++k)
        acc = fmaf(h3[sub][k], w4[k * 32 + n], acc);
    t4[r * 32 + n] = acc;
}

// ---------------------------------------------------------------------------
// BN stats over t4 (32 cols) -> scale5/shift5. Single 1024-thread block.
// ---------------------------------------------------------------------------
__global__ __launch_bounds__(1024) void stats4_kernel(
    const float* __restrict__ t4,
    const float* __restrict__ gamma, const float* __restrict__ beta,
    float* __restrict__ sc, float* __restrict__ sh)
{
    __shared__ float redS[32][32];
    __shared__ float redQ[32][32];
    const int c = threadIdx.x & 31;
    const int chunk = threadIdx.x >> 5;    // 32 chunks x 64 rows
    float s = 0.f, q = 0.f;
#pragma unroll 4
    for (int r = chunk * 64; r < chunk * 64 + 64; ++r) {
        const float v = t4[r * 32 + c];
        s += v; q = fmaf(v, v, q);
    }
    redS[chunk][c] = s; redQ[chunk][c] = q;
    __syncthreads();
    if (threadIdx.x < 32) {
        float S = 0.f, Q = 0.f;
#pragma unroll
        for (int k = 0; k < 32; ++k) { S += redS[k][c]; Q += redQ[k][c]; }
        const float mean = S * (1.f / BATCH);
        const float var  = Q * (1.f / BATCH) - mean * mean;
        const float scv  = gamma[c] * rsqrtf(var + EPSF);
        sc[c] = scv;
        sh[c] = beta[c] - mean * scv;
    }
}

// ---------------------------------------------------------------------------
// h4 = relu(bn5(t4)); out = h4 @ w5 + b5. 8 rows per 256-thread block.
// ---------------------------------------------------------------------------
__global__ __launch_bounds__(256) void final_kernel(
    const float* __restrict__ t4,
    const float* __restrict__ sc5, const float* __restrict__ sh5,
    const float* __restrict__ w5, const float* __restrict__ b5,
    float* __restrict__ out)
{
    const int sub = threadIdx.x >> 5;
    const int n   = threadIdx.x & 31;
    const int r   = blockIdx.x * 8 + sub;
    float v = fmaf(t4[r * 32 + n], sc5[n], sh5[n]);
    v = fmaxf(v, 0.f) * w5[n];
#pragma unroll
    for (int off = 16; off > 0; off >>= 1)
        v += __shfl_xor(v, off);
    if (n == 0) out[r] = v + b5[0];
}

// ---------------------------------------------------------------------------
extern "C" void kernel_launch(void* const* d_in, const int* in_sizes, int n_in,
                              void* d_out, int out_size, void* d_ws, size_t ws_size,
                              hipStream_t stream) {
    const float* input_x    = (const float*)d_in[0];
    const int*   input_hash = (const int*)  d_in[1];
    const float* table      = (const float*)d_in[2];
    const float* W0         = (const float*)d_in[3];
    const float* W1         = (const float*)d_in[4];
    const float* gamma1     = (const float*)d_in[5];
    const float* beta1      = (const float*)d_in[6];
    const float* w3         = (const float*)d_in[7];
    const float* b3         = (const float*)d_in[8];
    const float* gamma4     = (const float*)d_in[9];
    const float* beta4      = (const float*)d_in[10];
    const float* w4         = (const float*)d_in[11];
    const float* b4         = (const float*)d_in[12];
    const float* gamma5     = (const float*)d_in[13];
    const float* beta5      = (const float*)d_in[14];
    const float* w5         = (const float*)d_in[15];
    const float* b5         = (const float*)d_in[16];

    float* out        = (float*)d_out;         // B
    float* io_inputs  = out + BATCH;           // B x 829 (raw, then normalized)

    float* ws       = (float*)d_ws;
    float* partials = ws;                      // 32*832*2
    float* scale1   = partials + 32 * 832 * 2; // 832
    float* shift1   = scale1 + 832;            // 832
    float* t3       = shift1 + 832;            // B*64
    float* sc4      = t3 + BATCH * 64;         // 64
    float* sh4      = sc4 + 64;                // 64
    float* t4       = sh4 + 64;                // B*32
    float* sc5      = t4 + BATCH * 32;         // 32
    float* sh5      = sc5 + 32;                // 32

    cross_kernel  <<<BATCH / 2, 256, 0, stream>>>(input_x, input_hash, table, W0, W1, io_inputs);
    stats1a_kernel<<<32,        256, 0, stream>>>(io_inputs, partials);
    stats1b_kernel<<<4,         256, 0, stream>>>(partials, gamma1, beta1, scale1, shift1);
    mlp1_kernel   <<<BATCH / 4, 256, 0, stream>>>(io_inputs, scale1, shift1, w3, b3, t3);
    stats3_kernel <<<1,        1024, 0, stream>>>(t3, gamma4, beta4, sc4, sh4);
    mlp2_kernel   <<<BATCH / 4, 128, 0, stream>>>(t3, sc4, sh4, w4, b4, t4);
    stats4_kernel <<<1,        1024, 0, stream>>>(t4, gamma5, beta5, sc5, sh5);
    final_kernel  <<<BATCH / 8, 256, 0, stream>>>(t4, sc5, sh5, w5, b5, out);
}